// Round 16
// baseline (103.330 us; speedup 1.0000x reference)
//
#include <hip/hip_runtime.h>

#define N_TOK 8192
#define IN_DIM 1024
#define OUT_DIM 1024
#define NE 8

typedef short short8 __attribute__((ext_vector_type(8)));
typedef float f32x4 __attribute__((ext_vector_type(4)));
typedef ushort ushort4v __attribute__((ext_vector_type(4)));

__device__ __forceinline__ ushort f2bf(float f) {
    union { float f; unsigned u; } v; v.f = f;
    unsigned u = v.u;
    unsigned r = (u + 0x7fffu + ((u >> 16) & 1u)) >> 16;
    return (ushort)r;
}

__device__ __forceinline__ float bf2f(short s) {
    union { unsigned u; float f; } v;
    v.u = ((unsigned)(unsigned short)s) << 16;
    return v.f;
}

__device__ __forceinline__ void gl_lds16(const short* g, short* l) {
    __builtin_amdgcn_global_load_lds(
        (const __attribute__((address_space(1))) unsigned int*)g,
        (__attribute__((address_space(3))) unsigned int*)l, 16, 0, 0);
}

// ---- fused prep: blocks 0..511 = gating (4 tok/wave, Wg reused in registers)
//      + x->bf16; blocks 512..8703 = W transpose -> FRAGMENT-ORDER wtf:
//      wtf[((e*64+nb)*32+kb)*512 + ks*128 + fr*8 + kr], lane l of a B-frag
//      (n=nb*16+fr=l&15, k=kb*32+(ks=l>>4)*8+kr) reads frag_base + l*16B. ----
__global__ __launch_bounds__(256) void prep(const float* __restrict__ x,
                                            const float* __restrict__ Wg,
                                            const float* __restrict__ bg,
                                            const float* __restrict__ W,
                                            short* __restrict__ xb,
                                            short* __restrict__ wtf,
                                            unsigned* __restrict__ choice,
                                            float2* __restrict__ wts) {
    __shared__ ushort tile[32][33];
    int bid = blockIdx.x;
    int t = threadIdx.x;
    if (bid < 512) {
        int wid = t >> 6, lane = t & 63;
        int tok0 = bid * 16 + wid * 4;
        float acc[4][8];
        #pragma unroll
        for (int tk = 0; tk < 4; ++tk)
            #pragma unroll
            for (int e = 0; e < 8; ++e) acc[tk][e] = 0.f;

        #pragma unroll
        for (int it = 0; it < 4; ++it) {
            int j = it * 256 + lane * 4;
            float4 wa[4], wb[4];
            #pragma unroll
            for (int r = 0; r < 4; ++r) {
                wa[r] = *(const float4*)(Wg + (size_t)(j + r) * 8);
                wb[r] = *(const float4*)(Wg + (size_t)(j + r) * 8 + 4);
            }
            #pragma unroll
            for (int tk = 0; tk < 4; ++tk) {
                const float* xr = x + (size_t)(tok0 + tk) * IN_DIM;
                float4 v = *(const float4*)(xr + j);
                ushort4v o;
                o[0] = f2bf(v.x); o[1] = f2bf(v.y); o[2] = f2bf(v.z); o[3] = f2bf(v.w);
                *(ushort4v*)(xb + (size_t)(tok0 + tk) * IN_DIM + j) = o;
                #pragma unroll
                for (int r = 0; r < 4; ++r) {
                    float xv = (r == 0) ? v.x : (r == 1) ? v.y : (r == 2) ? v.z : v.w;
                    acc[tk][0] += xv * wa[r].x; acc[tk][1] += xv * wa[r].y;
                    acc[tk][2] += xv * wa[r].z; acc[tk][3] += xv * wa[r].w;
                    acc[tk][4] += xv * wb[r].x; acc[tk][5] += xv * wb[r].y;
                    acc[tk][6] += xv * wb[r].z; acc[tk][7] += xv * wb[r].w;
                }
            }
        }
        #pragma unroll
        for (int tk = 0; tk < 4; ++tk)
            #pragma unroll
            for (int e = 0; e < 8; ++e)
                #pragma unroll
                for (int off = 32; off; off >>= 1)
                    acc[tk][e] += __shfl_xor(acc[tk][e], off, 64);
        if (lane == 0) {
            #pragma unroll
            for (int tk = 0; tk < 4; ++tk) {
                float s[8];
                #pragma unroll
                for (int e = 0; e < 8; ++e) s[e] = acc[tk][e] + bg[e];
                int i0 = 0;
                #pragma unroll
                for (int e = 1; e < 8; ++e) if (s[e] > s[i0]) i0 = e;
                int i1 = (i0 == 0) ? 1 : 0;
                #pragma unroll
                for (int e = 0; e < 8; ++e) if (e != i0 && s[e] > s[i1]) i1 = e;
                float e0 = 1.f, e1 = __expf(s[i1] - s[i0]);
                float inv = 1.f / (e0 + e1);
                choice[tok0 + tk] = (unsigned)i0 | ((unsigned)i1 << 8);
                wts[tok0 + tk] = make_float2(e0 * inv, e1 * inv);
            }
        }
    } else {
        int id = bid - 512;
        int nt = id & 31, kt = (id >> 5) & 31, e = id >> 10;
        int r = t >> 3;
        int c4 = (t & 7) * 4;
        const float4 v = *(const float4*)(W + (((size_t)e * 1024 + kt * 32 + r) * 1024) + nt * 32 + c4);
        tile[c4 + 0][r] = f2bf(v.x);
        tile[c4 + 1][r] = f2bf(v.y);
        tile[c4 + 2][r] = f2bf(v.z);
        tile[c4 + 3][r] = f2bf(v.w);
        __syncthreads();
        int n = nt * 32 + (t >> 3);
        int kq = (t & 7) * 4;                 // k within the 32-k tile
        int nb = n >> 4, fr = n & 15;
        int ks = kq >> 3, kr = kq & 7;        // kr in {0,4}: ushort4 stays in-run
        ushort4v o;
        o[0] = tile[t >> 3][kq + 0]; o[1] = tile[t >> 3][kq + 1];
        o[2] = tile[t >> 3][kq + 2]; o[3] = tile[t >> 3][kq + 3];
        *(ushort4v*)(wtf + (((size_t)e * 64 + nb) * 32 + kt) * 512
                     + ks * 128 + fr * 8 + kr) = o;
    }
}

// ---- bucketing: preloaded chunks, deterministic ballot prefix, no atomics ----
__global__ __launch_bounds__(1024) void bucket(const unsigned* __restrict__ choice,
                                               int* __restrict__ counts,
                                               int* __restrict__ entries,
                                               int* __restrict__ inv0,
                                               int* __restrict__ inv1) {
    int e = blockIdx.x;
    int t = threadIdx.x;
    int wid = t >> 6, lane = t & 63;
    __shared__ int wsum[16];
    unsigned c[8];
    #pragma unroll
    for (int chunk = 0; chunk < 8; ++chunk) c[chunk] = choice[chunk * 1024 + t];
    int base = 0;
    #pragma unroll
    for (int chunk = 0; chunk < 8; ++chunk) {
        int tok = chunk * 1024 + t;
        int which = ((int)(c[chunk] & 255u) == e) ? 0
                  : (((int)((c[chunk] >> 8) & 255u) == e) ? 1 : -1);
        unsigned long long m = __ballot(which >= 0);
        if (lane == 0) wsum[wid] = __popcll(m);
        __syncthreads();
        int woff = base;
        #pragma unroll
        for (int i = 0; i < 16; ++i) if (i < wid) woff += wsum[i];
        int tot = 0;
        #pragma unroll
        for (int i = 0; i < 16; ++i) tot += wsum[i];
        if (which >= 0) {
            int rank = __popcll(m & ((1ull << lane) - 1ull));
            int idx = woff + rank;
            entries[e * N_TOK + idx] = tok;
            if (which == 0) inv0[tok] = idx; else inv1[tok] = idx;
        }
        base += tot;
        __syncthreads();
    }
    if (t == 0) counts[e] = base;
}

// ---- grouped GEMM: 128x256 tile, BK=32, 4 waves (2x2, 64x128 each).
//      BARRIER-FREE K-loop: B-frags global->reg (pre-fragmented wtf,
//      reg ping-pong cbfE/cbfO); A staged into PER-WAVE PRIVATE 2-ring
//      LDS (each wave stages only rows it reads) -> only per-wave
//      vmcnt(12) sync. Waves free-run; phases overlap across waves. ----
__global__ __launch_bounds__(256, 2) void moe_gemm(const short* __restrict__ xb,
                                                   const short* __restrict__ wtf,
                                                   const float* __restrict__ bias,
                                                   const int* __restrict__ counts,
                                                   const int* __restrict__ entries,
                                                   short* __restrict__ ys) {
    int lin = blockIdx.x;
    int e = lin & 7;
    int inner = lin >> 3;
    int ct = inner & 3, rt = inner >> 2;
    int cnt = counts[e];
    if (rt * 128 >= cnt) return;
    int rows = min(128, cnt - rt * 128);
    int base_e = 0;
    #pragma unroll
    for (int i = 0; i < NE; ++i) base_e += (i < e) ? counts[i] : 0;

    // union: 4 waves x 2-ring x 2048 shorts = 16384; epilogue 128x268 = 34304
    __shared__ __align__(16) short lds[34304];
    __shared__ int tok_sh[128];

    int t = threadIdx.x, wid = t >> 6, lane = t & 63;
    int ebase = e * N_TOK + rt * 128;
    if (t < 128) tok_sh[t] = (t < rows) ? entries[ebase + t] : entries[ebase];
    __syncthreads();

    int wr = wid >> 1, wc = wid & 1;       // 2x2 waves; 64 rows x 128 cols each
    int frow = lane & 15, fslot = lane >> 4;

    // ---- private-A staging: 4 gl_lds/iter; instr i covers local rows
    // i*16+(lane>>2), chunk lane&3; src k-chunk pre-swizzled ----
    int chunkoff = (((lane & 3) ^ ((lane >> 2) & 3)) * 8);
    const short* asrc[4];
    #pragma unroll
    for (int i = 0; i < 4; ++i)
        asrc[i] = xb + (size_t)tok_sh[wr * 64 + i * 16 + (lane >> 2)] * IN_DIM + chunkoff;
    short* apriv = lds + wid * 4096;       // 2 x 2048-short ring
    int adst = lane * 8;                   // + i*512 per instr, + par*2048

    // ---- A-frag read offsets (reader XOR mirrors stage pre-swizzle) ----
    int rslot = ((fslot ^ (frow & 3)) * 8);
    int aoff[4];
    #pragma unroll
    for (int mi = 0; mi < 4; ++mi) aoff[mi] = (mi * 16 + frow) * 32 + rslot;

    // ---- B-frag global pointers: frag (e, nb=ct*16+wc*8+ni, kb=kt) at
    // wtf + ((e*64+nb)*32+kt)*512 + lane*8 ----
    const short* bbase = wtf + ((size_t)e * 64 + ct * 16 + wc * 8) * 32 * 512 + lane * 8;

    f32x4 acc[4][8];
    #pragma unroll
    for (int mi = 0; mi < 4; ++mi)
        #pragma unroll
        for (int ni = 0; ni < 8; ++ni) acc[mi][ni] = (f32x4)(0.0f);

    short8 caf[4], cbfE[8], cbfO[8];

#define STAGEA(PAR, KT)                                                       \
    {                                                                         \
        short* ab = apriv + (PAR) * 2048;                                     \
        int nk = (KT) * 32;                                                   \
        gl_lds16(asrc[0] + nk, ab + adst);                                    \
        gl_lds16(asrc[1] + nk, ab + 512 + adst);                              \
        gl_lds16(asrc[2] + nk, ab + 1024 + adst);                             \
        gl_lds16(asrc[3] + nk, ab + 1536 + adst);                             \
    }

#define LOADB(KT, CBF)                                                        \
    {                                                                         \
        const short* bp = bbase + (size_t)(KT) * 512;                         \
        _Pragma("unroll")                                                     \
        for (int ni = 0; ni < 8; ++ni)                                        \
            CBF[ni] = *(const short8*)(bp + (size_t)ni * 16384);              \
    }

// iter t (parity PAR = t&1): issue A-stage(t+1)->ring PAR^1 and B-load(t+1)
// ->CBFN; vmcnt(12) = the 12 just issued stay in flight, prior iter's A(t)
// landed in ring PAR (B(t) regs auto-waited by compiler); ds_read A-frags(t);
// 32 MFMA. No barriers: all LDS is wave-private, program-ordered.
#define AITER(PAR, KTN, CBFC, CBFN, DO_NEXT, VN)                              \
    {                                                                         \
        if (DO_NEXT) { STAGEA((PAR) ^ 1, KTN); LOADB(KTN, CBFN); }            \
        asm volatile("s_waitcnt vmcnt(" VN ")" ::: "memory");                 \
        const short* ab = apriv + (PAR) * 2048;                               \
        _Pragma("unroll")                                                     \
        for (int mi = 0; mi < 4; ++mi) caf[mi] = *(const short8*)(ab + aoff[mi]); \
        _Pragma("unroll")                                                     \
        for (int mi = 0; mi < 4; ++mi)                                        \
            _Pragma("unroll")                                                 \
            for (int ni = 0; ni < 8; ++ni)                                    \
                acc[mi][ni] = __builtin_amdgcn_mfma_f32_16x16x32_bf16(        \
                    caf[mi], CBFC[ni], acc[mi][ni], 0, 0, 0);                 \
    }

    // prologue: stage A(0) ring0, load B(0)->cbfE
    STAGEA(0, 0);
    LOADB(0, cbfE);

    for (int p = 0; p < 15; ++p) {
        AITER(0, 2 * p + 1, cbfE, cbfO, 1, "12");
        AITER(1, 2 * p + 2, cbfO, cbfE, 1, "12");
    }
    AITER(0, 31, cbfE, cbfO, 1, "12");    // t=30
    AITER(1, 0, cbfO, cbfE, 0, "0");      // t=31

#undef AITER
#undef LOADB
#undef STAGEA

    // ---- epilogue: acc -> LDS stride 268 (conflict-free) -> 16B bursts ----
    __syncthreads();
    short* ep = lds;
    const float* be = bias + (size_t)e * OUT_DIM;
    #pragma unroll
    for (int ni = 0; ni < 8; ++ni) {
        int col = wc * 128 + ni * 16 + frow;
        float bv = be[ct * 256 + col];
        #pragma unroll
        for (int mi = 0; mi < 4; ++mi) {
            int rb_ = wr * 64 + mi * 16 + fslot * 4;
            #pragma unroll
            for (int r = 0; r < 4; ++r)
                ep[(rb_ + r) * 268 + col] = (short)f2bf(acc[mi][ni][r] + bv);
        }
    }
    __syncthreads();
    #pragma unroll
    for (int k = 0; k < 16; ++k) {
        int f = t + k * 256;
        int row = f >> 5, cw = f & 31;
        if (row < rows) {
            short8 v = *(const short8*)(ep + row * 268 + cw * 8);
            *(short8*)(ys + ((size_t)(base_e + rt * 128 + row)) * OUT_DIM
                       + ct * 256 + cw * 8) = v;
        }
    }
}

// ---- combine: out[tok] = w0*ys[pos0] + w1*ys[pos1] ----
__global__ __launch_bounds__(256) void combine(const short* __restrict__ ys,
                                               const unsigned* __restrict__ choice,
                                               const float2* __restrict__ wts,
                                               const int* __restrict__ inv0,
                                               const int* __restrict__ inv1,
                                               const int* __restrict__ counts,
                                               float* __restrict__ out) {
    __shared__ int bases[8];
    if (threadIdx.x < 8) {
        int s = 0;
        #pragma unroll
        for (int i = 0; i < 8; ++i) s += (i < (int)threadIdx.x) ? counts[i] : 0;
        bases[threadIdx.x] = s;
    }
    __syncthreads();
    int tok = blockIdx.x * 2 + (threadIdx.x >> 7);
    int c8 = (threadIdx.x & 127) * 8;
    unsigned ch = choice[tok];
    float2 w = wts[tok];
    int p0 = bases[ch & 255u] + inv0[tok];
    int p1 = bases[(ch >> 8) & 255u] + inv1[tok];
    short8 a = *(const short8*)(ys + (size_t)p0 * OUT_DIM + c8);
    short8 b = *(const short8*)(ys + (size_t)p1 * OUT_DIM + c8);
    float* op = out + (size_t)tok * OUT_DIM + c8;
    float4 o0, o1;
    o0.x = w.x * bf2f(a[0]) + w.y * bf2f(b[0]);
    o0.y = w.x * bf2f(a[1]) + w.y * bf2f(b[1]);
    o0.z = w.x * bf2f(a[2]) + w.y * bf2f(b[2]);
    o0.w = w.x * bf2f(a[3]) + w.y * bf2f(b[3]);
    o1.x = w.x * bf2f(a[4]) + w.y * bf2f(b[4]);
    o1.y = w.x * bf2f(a[5]) + w.y * bf2f(b[5]);
    o1.z = w.x * bf2f(a[6]) + w.y * bf2f(b[6]);
    o1.w = w.x * bf2f(a[7]) + w.y * bf2f(b[7]);
    *(float4*)op = o0;
    *(float4*)(op + 4) = o1;
}

extern "C" void kernel_launch(void* const* d_in, const int* in_sizes, int n_in,
                              void* d_out, int out_size, void* d_ws, size_t ws_size,
                              hipStream_t stream) {
    const float* x  = (const float*)d_in[0];
    const float* W  = (const float*)d_in[1];
    const float* b  = (const float*)d_in[2];
    const float* Wg = (const float*)d_in[3];
    const float* bg = (const float*)d_in[4];
    float* out = (float*)d_out;

    char* ws = (char*)d_ws;
    short* xb        = (short*)(ws);                     // 16 MiB
    short* wtf       = (short*)(ws + 16777216);          // 16 MiB (fragment order)
    unsigned* choice = (unsigned*)(ws + 33554432);       // 32 KiB
    float2* wts      = (float2*)(ws + 33587200);         // 64 KiB
    int* inv0        = (int*)(ws + 33652736);            // 32 KiB
    int* inv1        = (int*)(ws + 33685504);            // 32 KiB
    int* entries     = (int*)(ws + 33718272);            // 256 KiB
    int* counts      = (int*)(ws + 34242560);            // 64 B
    short* ys        = (short*)(ws + 34242624);          // 32 MiB

    prep<<<8704, 256, 0, stream>>>(x, Wg, bg, W, xb, wtf, choice, wts);
    bucket<<<8, 1024, 0, stream>>>(choice, counts, entries, inv0, inv1);
    moe_gemm<<<2048, 256, 0, stream>>>(xb, wtf, b, counts, entries, ys);
    combine<<<4096, 256, 0, stream>>>(ys, choice, wts, inv0, inv1, counts, out);
}